// Round 5
// baseline (185.453 us; speedup 1.0000x reference)
//
#include <hip/hip_runtime.h>

#define Bb 64
#define Nn 1152
#define Oo 32
#define DOv 16
#define DIv 8
#define BPB 32   // b's per block: 4 waves x NG b's (wave-uniform b sets)
#define NG 8     // b's per thread

// async global->LDS, 16B per lane
__device__ __forceinline__ void gload_lds16(const void* g, void* l) {
    __builtin_amdgcn_global_load_lds(
        (const __attribute__((address_space(1))) unsigned*)g,
        (__attribute__((address_space(3))) unsigned*)l, 16, 0, 0);
}

// One routing iteration. Lane layout: o = t&31, ih = (t>>5)&1 (i-half), wave wv.
// Thread covers b = b0 + wv*NG + g (g=0..7), i-range ih*8..ih*8+7.
// vcum == nullptr -> uniform c = 1/32 (iteration 1).
__global__ __launch_bounds__(256, 2) void caps_route(
    const float* __restrict__ x,     // [B, N, DI]
    const float* __restrict__ w,     // [N, O, DO, DI]
    const float* __restrict__ vcum,  // [B, O, DO] or nullptr
    float* __restrict__ spart,       // [nch, B, O, DO]
    int nc)
{
    const int t  = threadIdx.x;
    const int o  = t & 31;
    const int ih = (t >> 5) & 1;
    const int wv = __builtin_amdgcn_readfirstlane(t >> 6);   // wave id 0..3
    const int n0 = blockIdx.x * nc;
    const int b0 = blockIdx.y * BPB + wv * NG;               // wave-uniform

    // Swizzled W tiles: phys float4 slot o*32 + (i2^o) holds logical w[n][o][i2].
    // Staging keeps LDS dest lane-linear; the GLOBAL index is pre-swizzled (gq).
    __shared__ float4 wbuf[2][2][1024];   // [dbuf][n-sub][slot] = 64 KB

    int gq[4];
#pragma unroll
    for (int k = 0; k < 4; ++k) {
        int p = k * 256 + t;
        gq[k] = (p & ~31) | ((p ^ (p >> 5)) & 31);
    }
    auto stageW2 = [&](int n, int c) {   // stage n, n+1 into wbuf[c][0..1]
#pragma unroll
        for (int s2 = 0; s2 < 2; ++s2) {
            const float4* wg = (const float4*)(w + (size_t)(n + s2) * (Oo * DOv * DIv));
#pragma unroll
            for (int k = 0; k < 4; ++k)
                gload_lds16(&wg[gq[k]], &wbuf[c][s2][k * 256 + t]);
        }
    };

    const bool have_v = (vcum != nullptr);
    float sacc[NG][8];
#pragma unroll
    for (int g = 0; g < NG; ++g)
#pragma unroll
        for (int i = 0; i < 8; ++i) sacc[g][i] = 0.f;

    stageW2(n0, 0);
    __syncthreads();                       // drain: buf0 ready
    int cur = 0;

    for (int pp = 0; pp < (nc >> 1); ++pp) {
        if (pp + 1 < (nc >> 1)) stageW2(n0 + 2 * pp + 2, cur ^ 1);  // fly under compute

#pragma unroll
        for (int s2 = 0; s2 < 2; ++s2) {
            const int n = n0 + 2 * pp + s2;

            // x rows: wave-uniform addresses -> scalar/L1 loads, no LDS
            float xs[NG][DIv];
#pragma unroll
            for (int g = 0; g < NG; ++g) {
                const float* xp = x + ((size_t)(b0 + g) * Nn + n) * DIv;
#pragma unroll
                for (int j = 0; j < DIv; ++j) xs[g][j] = xp[j];
            }

            // xh[g][ii] for global i = ih*8+ii ; 16 swizzled b128 W reads
            float xh[NG][8];
#pragma unroll
            for (int g = 0; g < NG; ++g)
#pragma unroll
                for (int i = 0; i < 8; ++i) xh[g][i] = 0.f;
#pragma unroll
            for (int k = 0; k < 16; ++k) {
                const int i2 = ih * 16 + k;
                float4 wv4 = wbuf[cur][s2][o * 32 + ((i2 ^ o) & 31)];
                const int ii = k >> 1, jb = (k & 1) * 4;
#pragma unroll
                for (int g = 0; g < NG; ++g) {
                    xh[g][ii] = fmaf(wv4.x, xs[g][jb + 0], xh[g][ii]);
                    xh[g][ii] = fmaf(wv4.y, xs[g][jb + 1], xh[g][ii]);
                    xh[g][ii] = fmaf(wv4.z, xs[g][jb + 2], xh[g][ii]);
                    xh[g][ii] = fmaf(wv4.w, xs[g][jb + 3], xh[g][ii]);
                }
            }

            float c[NG];
            if (have_v) {
                // logit partial over this lane's i-half, combine across halves
                float l[NG];
#pragma unroll
                for (int g = 0; g < NG; ++g) {
                    const float* vp = vcum + (((size_t)(b0 + g) * Oo + o) * DOv + ih * 8);
                    float4 v0 = ((const float4*)vp)[0], v1 = ((const float4*)vp)[1];
                    float lp = xh[g][0] * v0.x + xh[g][1] * v0.y + xh[g][2] * v0.z + xh[g][3] * v0.w
                             + xh[g][4] * v1.x + xh[g][5] * v1.y + xh[g][6] * v1.z + xh[g][7] * v1.w;
                    l[g] = lp + __shfl_xor(lp, 32);
                }
                float e[NG];
#pragma unroll
                for (int g = 0; g < NG; ++g) e[g] = __expf(l[g]);  // |l| < 1: no max-sub

                // denominator: each half reduces 4 g's over its 32 o-lanes, then exchange
                float r[4];
#pragma unroll
                for (int k4 = 0; k4 < 4; ++k4) r[k4] = ih ? e[k4 + 4] : e[k4];
#pragma unroll
                for (int d = 16; d >= 1; d >>= 1)
#pragma unroll
                    for (int k4 = 0; k4 < 4; ++k4) r[k4] += __shfl_xor(r[k4], d);
                float ro[4];
#pragma unroll
                for (int k4 = 0; k4 < 4; ++k4) ro[k4] = __shfl_xor(r[k4], 32);
#pragma unroll
                for (int k4 = 0; k4 < 4; ++k4) {
                    float slo = ih ? ro[k4] : r[k4];   // sum for g = k4
                    float shi = ih ? r[k4] : ro[k4];   // sum for g = k4+4
                    c[k4]     = e[k4]     * __builtin_amdgcn_rcpf(slo);
                    c[k4 + 4] = e[k4 + 4] * __builtin_amdgcn_rcpf(shi);
                }
            } else {
#pragma unroll
                for (int g = 0; g < NG; ++g) c[g] = 1.0f / 32.0f;
            }

#pragma unroll
            for (int g = 0; g < NG; ++g)
#pragma unroll
                for (int i = 0; i < 8; ++i) sacc[g][i] += c[g] * xh[g][i];
        }
        __syncthreads();   // next stage drained; wbuf[cur] free for restage
        cur ^= 1;
    }

    // store partial s (no atomics): 2 float4 per g
    float* p = spart + (size_t)blockIdx.x * (Bb * Oo * DOv);
#pragma unroll
    for (int g = 0; g < NG; ++g) {
        float* pg = p + (((size_t)(b0 + g) * Oo + o) * DOv + ih * 8);
        ((float4*)pg)[0] = make_float4(sacc[g][0], sacc[g][1], sacc[g][2], sacc[g][3]);
        ((float4*)pg)[1] = make_float4(sacc[g][4], sacc[g][5], sacc[g][6], sacc[g][7]);
    }
}

// Reduce nch partials + squash. One wave per (b, o); float4 lanes: q = t&3, pg = t>>2.
__global__ __launch_bounds__(64) void caps_squash(
    const float* __restrict__ spart, int nch,
    const float* __restrict__ vin,   // may be nullptr (treated as 0)
    float* __restrict__ vout,        // may be nullptr
    float* __restrict__ out)         // may be nullptr
{
    const int b = blockIdx.x, oo = blockIdx.y;
    const int t = threadIdx.x;
    const int q = t & 3, pg = t >> 2;          // 16 p-groups
    const size_t base4 = ((size_t)b * Oo + oo) * (DOv / 4) + q;
    const float4* sp4 = (const float4*)spart;
    const size_t chunk4 = (size_t)Bb * Oo * DOv / 4;

    float4 s = make_float4(0.f, 0.f, 0.f, 0.f);
    for (int p = pg; p < nch; p += 16) {
        float4 v = sp4[(size_t)p * chunk4 + base4];
        s.x += v.x; s.y += v.y; s.z += v.z; s.w += v.w;
    }
#pragma unroll
    for (int d = 4; d <= 32; d <<= 1) {
        s.x += __shfl_xor(s.x, d); s.y += __shfl_xor(s.y, d);
        s.z += __shfl_xor(s.z, d); s.w += __shfl_xor(s.w, d);
    }
    float n2 = s.x * s.x + s.y * s.y + s.z * s.z + s.w * s.w;
    n2 += __shfl_xor(n2, 1);
    n2 += __shfl_xor(n2, 2);
    float sc = n2 / ((1.f + n2) * sqrtf(n2 + 1e-7f));
    if (t < 4) {
        float4 vj = make_float4(s.x * sc, s.y * sc, s.z * sc, s.w * sc);
        size_t i4 = base4;
        if (vout) {
            float4 vi = vin ? ((const float4*)vin)[i4] : make_float4(0.f, 0.f, 0.f, 0.f);
            ((float4*)vout)[i4] = make_float4(vi.x + vj.x, vi.y + vj.y, vi.z + vj.z, vi.w + vj.w);
        }
        if (out) ((float4*)out)[i4] = vj;
    }
}

extern "C" void kernel_launch(void* const* d_in, const int* in_sizes, int n_in,
                              void* d_out, int out_size, void* d_ws, size_t ws_size,
                              hipStream_t stream)
{
    const float* x = (const float*)d_in[0];
    const float* w = (const float*)d_in[1];
    float* out = (float*)d_out;

    // largest even-nc split whose partial buffer fits the workspace
    static const int cfgs[][2] = {{288,4},{144,8},{72,16},{36,32},{18,64},{8,144},{4,288},{2,576}};
    int nch = 2, nc = 576;
    for (auto& c : cfgs) {
        size_t need = ((size_t)c[0] * Bb * Oo * DOv + (size_t)Bb * Oo * DOv) * sizeof(float);
        if (need <= ws_size) { nch = c[0]; nc = c[1]; break; }
    }

    float* spart = (float*)d_ws;
    float* vcum  = spart + (size_t)nch * Bb * Oo * DOv;

    dim3 grid(nch, Bb / BPB), blk(256);
    dim3 sgrid(Bb, Oo), sblk(64);

    caps_route<<<grid, blk, 0, stream>>>(x, w, nullptr, spart, nc);
    caps_squash<<<sgrid, sblk, 0, stream>>>(spart, nch, nullptr, vcum, nullptr);
    caps_route<<<grid, blk, 0, stream>>>(x, w, vcum, spart, nc);
    caps_squash<<<sgrid, sblk, 0, stream>>>(spart, nch, vcum, vcum, nullptr);
    caps_route<<<grid, blk, 0, stream>>>(x, w, vcum, spart, nc);
    caps_squash<<<sgrid, sblk, 0, stream>>>(spart, nch, nullptr, nullptr, out);
}